// Round 1
// baseline (1382.852 us; speedup 1.0000x reference)
//
#include <hip/hip_runtime.h>
#include <stdint.h>

// ---------- types ----------
typedef float f4   __attribute__((ext_vector_type(4)));
typedef float f2   __attribute__((ext_vector_type(2)));
typedef float f32x4 __attribute__((ext_vector_type(4)));
typedef short bfx8 __attribute__((ext_vector_type(8)));
typedef unsigned short u16;

// ---------- problem constants ----------
#define TAU_INV (1.0f/1.5f)
#define NTOK 9216
#define NTOKPAD 9280
#define AOUT ((size_t)75497472)   // 32*3*24*2*16*1024

// ---------- workspace offsets (bytes) ----------
#define OFF_CTR    ((size_t)0)
#define OFF_TOKKEY ((size_t)4096)
#define OFF_TOKG   ((size_t)40960)
#define OFF_ROWTOK ((size_t)114688)
#define OFF_ROWG   ((size_t)151808)
#define OFF_G1E    ((size_t)226048)
#define OFF_AMAT   ((size_t)373504)
#define OFF_W2N    ((size_t)5124864)
#define OFF_W2TN   ((size_t)38679296)
#define OFF_B2T    ((size_t)72233728)
// total ws need ~72.8 MB

// counter layout (int indices)
#define C_CNTPAIR 0
#define C_OFFPAIR 128
#define C_CURPAIR 256
#define C_CNTEXP  384
#define C_OFFEXP  392
#define C_CUREXP  400
#define C_PSUM    408
#define C_LSUM    432

__device__ __forceinline__ u16 f2bf(float f) {
  uint32_t u = __builtin_bit_cast(uint32_t, f);
  u += 0x7FFFu + ((u >> 16) & 1u);
  return (u16)(u >> 16);
}

// ---------- zero counters ----------
__global__ void kzero(int* __restrict__ ctr) {
  ctr[threadIdx.x] = 0;   // 512 ints covers all counters
}

// ---------- W2 -> bf16 k-major copies (normal + output-permuted) ----------
// W2n[e][c][k]  = bf16(W2[e][k][c])                c in [0,16384), k in [0,128)
// W2Tn[e][c'][k]= bf16(W2[e][k][r*1024+h]), c'=h*16+r
__global__ __launch_bounds__(256) void kprep_w2(const float* __restrict__ W2,
        u16* __restrict__ W2n, u16* __restrict__ W2Tn) {
  int ct = blockIdx.x, kt = blockIdx.y, e = blockIdx.z;
  __shared__ float tile[32][33];
  int t = threadIdx.x;
  {
    int k = t >> 3, c4 = (t & 7) * 4;
    f4 v = *(const f4*)(W2 + ((size_t)(e*128 + kt*32 + k) * 16384) + ct*32 + c4);
    tile[k][c4] = v.x; tile[k][c4+1] = v.y; tile[k][c4+2] = v.z; tile[k][c4+3] = v.w;
  }
  __syncthreads();
  int c = t >> 3, k4 = (t & 7) * 4;
  int cg = ct*32 + c;
  ushort4 o;
  o.x = f2bf(tile[k4+0][c]); o.y = f2bf(tile[k4+1][c]);
  o.z = f2bf(tile[k4+2][c]); o.w = f2bf(tile[k4+3][c]);
  *(ushort4*)(W2n + ((size_t)(e*16384 + cg) * 128) + kt*32 + k4) = o;
  int r = cg >> 10, h = cg & 1023;
  int cp = h*16 + r;
  *(ushort4*)(W2Tn + ((size_t)(e*16384 + cp) * 128) + kt*32 + k4) = o;
}

// ---------- b2 permuted copy ----------
__global__ void kprep_b2(const float* __restrict__ b2, float* __restrict__ b2T) {
  int idx = blockIdx.x * 256 + threadIdx.x;   // 0..131071
  int e = idx >> 14, cp = idx & 16383;
  int h = cp >> 4, r = cp & 15;
  b2T[idx] = b2[(e << 14) + (r << 10) + h];
}

// ---------- routing: logits, top-2, gates, aux stats ----------
__global__ __launch_bounds__(256) void kroute(const float* __restrict__ z,
    const float* __restrict__ emb, const float* __restrict__ Wr,
    const float* __restrict__ br, int* __restrict__ ctr,
    int* __restrict__ tokKey, f2* __restrict__ tokG) {
  __shared__ float lg[64][8];
  __shared__ float lp[24], ll[24];
  int tid = threadIdx.x;
  int tk = tid >> 2, ep = tid & 3;
  int t = blockIdx.x * 64 + tk;
  int n = t % 288;
  const float* xz = z + (size_t)t * 256;
  const float* xe = emb + (size_t)n * 256;
  float a0 = 0.f, a1 = 0.f;
  for (int i = 0; i < 256; i += 4) {
    f4 x4 = *(const f4*)(xz + i);
    #pragma unroll
    for (int j = 0; j < 4; ++j) {
      f2 w = *(const f2*)(Wr + (i + j) * 8 + ep * 2);
      a0 += x4[j] * w.x; a1 += x4[j] * w.y;
    }
  }
  for (int i = 0; i < 256; i += 4) {
    f4 x4 = *(const f4*)(xe + i);
    #pragma unroll
    for (int j = 0; j < 4; ++j) {
      f2 w = *(const f2*)(Wr + (256 + i + j) * 8 + ep * 2);
      a0 += x4[j] * w.x; a1 += x4[j] * w.y;
    }
  }
  lg[tk][ep*2] = a0; lg[tk][ep*2+1] = a1;
  if (tid < 24) { lp[tid] = 0.f; ll[tid] = 0.f; }
  __syncthreads();
  if (tid < 64) {
    int tt = blockIdx.x * 64 + tid;
    int nn = tt % 288;
    int s = nn / 96;
    float le[8];
    #pragma unroll
    for (int e = 0; e < 8; ++e) le[e] = (lg[tid][e] + br[e]) * TAU_INV;
    int e0 = 0; float v0 = le[0];
    #pragma unroll
    for (int e = 1; e < 8; ++e) if (le[e] > v0) { v0 = le[e]; e0 = e; }
    int e1 = -1; float v1 = -1e30f;
    #pragma unroll
    for (int e = 0; e < 8; ++e) if (e != e0 && le[e] > v1) { v1 = le[e]; e1 = e; }
    float se = 0.f, pe[8];
    #pragma unroll
    for (int e = 0; e < 8; ++e) { pe[e] = expf(le[e] - v0); se += pe[e]; }
    float inv = 1.f / se;
    #pragma unroll
    for (int e = 0; e < 8; ++e) atomicAdd(&lp[s*8+e], pe[e] * inv);
    float g0 = 1.f / (1.f + expf(v1 - v0));
    float g1 = 1.f - g0;
    atomicAdd(&ll[s*8+e0], g0);
    atomicAdd(&ll[s*8+e1], g1);
    int emin = min(e0,e1), emax = max(e0,e1);
    float gmin = (e0 < e1) ? g0 : g1;
    float gmax = (e0 < e1) ? g1 : g0;
    int key = (emin*8 + emax)*2 + (nn & 1);
    tokKey[tt] = key;
    f2 g; g.x = gmin; g.y = gmax;
    tokG[tt] = g;
    atomicAdd(&ctr[C_CNTPAIR + key], 1);
    atomicAdd(&ctr[C_CNTEXP + emin], 1);
    atomicAdd(&ctr[C_CNTEXP + emax], 1);
  }
  __syncthreads();
  if (tid < 24) {
    if (lp[tid] != 0.f) atomicAdd((float*)&ctr[C_PSUM + tid], lp[tid]);
    if (ll[tid] != 0.f) atomicAdd((float*)&ctr[C_LSUM + tid], ll[tid]);
  }
}

// ---------- exclusive scans (tiny) ----------
__global__ void kscan(int* ctr) {
  int acc = 0;
  for (int k = 0; k < 128; ++k) { ctr[C_OFFPAIR + k] = acc; acc += ctr[C_CNTPAIR + k]; }
  acc = 0;
  for (int e = 0; e < 8; ++e) { ctr[C_OFFEXP + e] = acc; acc += ctr[C_CNTEXP + e]; }
}

// ---------- scatter: token -> pair-sorted row + per-expert GEMM1 entries ----------
__global__ __launch_bounds__(256) void kscatter(int* __restrict__ ctr,
    const int* __restrict__ tokKey, const f2* __restrict__ tokG,
    int* __restrict__ rowToken, f2* __restrict__ rowG, int2* __restrict__ g1e) {
  int t = blockIdx.x * 256 + threadIdx.x;
  if (t >= NTOK) return;
  int key = tokKey[t];
  int pos = atomicAdd(&ctr[C_CURPAIR + key], 1);
  int row = ctr[C_OFFPAIR + key] + pos;
  rowToken[row] = t;
  rowG[row] = tokG[t];
  int pair = key >> 1, emin = pair >> 3, emax = pair & 7;
  int p0 = atomicAdd(&ctr[C_CUREXP + emin], 1);
  int2 en0; en0.x = row*2;     en0.y = t;
  g1e[ctr[C_OFFEXP + emin] + p0] = en0;
  int p1 = atomicAdd(&ctr[C_CUREXP + emax], 1);
  int2 en1; en1.x = row*2 + 1; en1.y = t;
  g1e[ctr[C_OFFEXP + emax] + p1] = en1;
}

// ---------- GEMM1: per-expert grouped (entries x 512) @ W1[e] -> silu -> *gate -> bf16 Amat ----------
__global__ __launch_bounds__(256) void kgemm1(const float* __restrict__ z,
    const float* __restrict__ emb, const float* __restrict__ W1,
    const float* __restrict__ b1, const int* __restrict__ ctr,
    const int2* __restrict__ g1e, const f2* __restrict__ rowG,
    u16* __restrict__ Amat) {
  int e = blockIdx.y;
  int cnt = ctr[C_CNTEXP + e];
  int mt = blockIdx.x;
  if (mt * 64 >= cnt) return;
  int base = ctr[C_OFFEXP + e];
  __shared__ float xs[64][32];
  __shared__ float w1s[32][132];
  int tid = threadIdx.x;
  int strow = tid >> 2, ks = (tid & 3) * 8;
  int sidx = min(mt*64 + strow, cnt - 1);
  int stok = g1e[base + sidx].y;
  const float* xz = z + (size_t)stok * 256;
  const float* xe = emb + (size_t)(stok % 288) * 256;
  int kw = tid >> 3, cw = (tid & 7) * 16;
  const float* wbase = W1 + (size_t)e * 512 * 128;
  int r0 = (tid >> 5) * 8, c0 = (tid & 31) * 4;
  f32x4 acc[8];
  #pragma unroll
  for (int r = 0; r < 8; ++r) { f32x4 zv = {0.f,0.f,0.f,0.f}; acc[r] = zv; }
  for (int kc = 0; kc < 16; ++kc) {
    int k0 = kc * 32;
    __syncthreads();
    {
      const float* src = (k0 < 256) ? (xz + k0 + ks) : (xe + (k0 - 256) + ks);
      f4 v0 = *(const f4*)(src);
      f4 v1 = *(const f4*)(src + 4);
      *(f4*)&xs[strow][ks]     = v0;
      *(f4*)&xs[strow][ks + 4] = v1;
      const float* wp = wbase + (size_t)(k0 + kw) * 128 + cw;
      f4 w0 = *(const f4*)(wp);
      f4 w1v = *(const f4*)(wp + 4);
      f4 w2v = *(const f4*)(wp + 8);
      f4 w3v = *(const f4*)(wp + 12);
      *(f4*)&w1s[kw][cw]      = w0;
      *(f4*)&w1s[kw][cw + 4]  = w1v;
      *(f4*)&w1s[kw][cw + 8]  = w2v;
      *(f4*)&w1s[kw][cw + 12] = w3v;
    }
    __syncthreads();
    #pragma unroll 8
    for (int kk = 0; kk < 32; ++kk) {
      f4 w = *(const f4*)&w1s[kk][c0];
      #pragma unroll
      for (int r = 0; r < 8; ++r) {
        float a = xs[r0 + r][kk];
        acc[r] += w * a;
      }
    }
  }
  f4 bb = *(const f4*)(b1 + e*128 + c0);
  #pragma unroll
  for (int r = 0; r < 8; ++r) {
    int idx = mt*64 + r0 + r;
    if (idx < cnt) {
      int2 ent = g1e[base + idx];
      int row = ent.x >> 1, half = ent.x & 1;
      f2 g = rowG[row];
      float gv = half ? g.y : g.x;
      ushort4 o;
      float h0 = acc[r][0] + bb[0]; h0 = h0 / (1.f + expf(-h0)) * gv; o.x = f2bf(h0);
      float h1 = acc[r][1] + bb[1]; h1 = h1 / (1.f + expf(-h1)) * gv; o.y = f2bf(h1);
      float h2 = acc[r][2] + bb[2]; h2 = h2 / (1.f + expf(-h2)) * gv; o.z = f2bf(h2);
      float h3 = acc[r][3] + bb[3]; h3 = h3 / (1.f + expf(-h3)) * gv; o.w = f2bf(h3);
      *(ushort4*)(Amat + (size_t)row * 256 + half * 128 + c0) = o;
    }
  }
}

// ---------- GEMM2: per-pair grouped (rows x 256) @ [W2[a];W2[b]] (k-major bf16) ----------
// B-tile (256x128 bf16 = 64KB) resident in LDS, XOR-swizzled; A-frags streamed from global.
__global__ __launch_bounds__(256) void kgemm2(
    const u16* __restrict__ Amat, const u16* __restrict__ Bkn,
    const float* __restrict__ bias, const int* __restrict__ ctr,
    const int* __restrict__ rowToken, const f2* __restrict__ rowG,
    float* __restrict__ outp, int isB) {
  int rem = blockIdx.y;     // 0..27 -> ordered pair (a<b)
  int a = 0, b = 0;
  for (a = 0; a < 8; ++a) { int c8 = 7 - a; if (rem < c8) { b = a + 1 + rem; break; } rem -= c8; }
  int key = (a*8 + b)*2 + isB;
  int cnt = ctr[C_CNTPAIR + key];
  if (cnt == 0) return;
  int rowStart = ctr[C_OFFPAIR + key];
  int c0 = blockIdx.x * 128;

  __shared__ uint4 BtV[4096];   // exactly 64 KB
  int tid = threadIdx.x;
  #pragma unroll
  for (int j = 0; j < 16; ++j) {
    int ch = tid + j*256;
    int n = ch >> 5, c = ch & 31;
    int ex = (c < 16) ? a : b;
    int kc = c & 15;
    uint4 v = *(const uint4*)(Bkn + ((size_t)(ex*16384 + c0 + n) * 128) + kc*8);
    BtV[(n << 5) + (c ^ (n & 31))] = v;
  }
  __syncthreads();

  int w = tid >> 6, lane = tid & 63;
  int quad = lane >> 4, l15 = lane & 15;
  int ncol0 = w*32 + l15, ncol1 = ncol0 + 16;
  float b2a0 = bias[a*16384 + c0 + ncol0];
  float b2a1 = bias[a*16384 + c0 + ncol1];
  float b2b0 = bias[b*16384 + c0 + ncol0];
  float b2b1 = bias[b*16384 + c0 + ncol1];

  const bfx8* BtH = (const bfx8*)BtV;
  int nIter = (cnt + 31) >> 5;
  for (int mch = 0; mch < nIter; ++mch) {
    f32x4 acc00 = {0,0,0,0}, acc01 = {0,0,0,0}, acc10 = {0,0,0,0}, acc11 = {0,0,0,0};
    size_t rbase0 = (size_t)(rowStart + mch*32 + l15) << 8;  // u16 units
    size_t rbase1 = rbase0 + ((size_t)16 << 8);
    #pragma unroll
    for (int kk = 0; kk < 8; ++kk) {
      int cc = kk*4 + quad;
      bfx8 av0 = *(const bfx8*)(Amat + rbase0 + cc*8);
      bfx8 av1 = *(const bfx8*)(Amat + rbase1 + cc*8);
      bfx8 bv0 = BtH[(ncol0 << 5) + (cc ^ (ncol0 & 31))];
      bfx8 bv1 = BtH[(ncol1 << 5) + (cc ^ (ncol1 & 31))];
      acc00 = __builtin_amdgcn_mfma_f32_16x16x32_bf16(av0, bv0, acc00, 0, 0, 0);
      acc01 = __builtin_amdgcn_mfma_f32_16x16x32_bf16(av0, bv1, acc01, 0, 0, 0);
      acc10 = __builtin_amdgcn_mfma_f32_16x16x32_bf16(av1, bv0, acc10, 0, 0, 0);
      acc11 = __builtin_amdgcn_mfma_f32_16x16x32_bf16(av1, bv1, acc11, 0, 0, 0);
    }
    #pragma unroll
    for (int mi = 0; mi < 2; ++mi) {
      f32x4 aN0 = mi ? acc10 : acc00;
      f32x4 aN1 = mi ? acc11 : acc01;
      #pragma unroll
      for (int r = 0; r < 4; ++r) {
        int mlocal = mch*32 + mi*16 + quad*4 + r;
        if (mlocal >= cnt) continue;
        int grow = rowStart + mlocal;
        int token = rowToken[grow];
        f2 g = rowG[grow];
        unsigned ut = (unsigned)token;
        unsigned bb = ut / 288u, nn = ut % 288u;
        unsigned s = nn / 96u, np = nn % 96u;
        unsigned l = np >> 2, q = np & 3;
        size_t obase = ((size_t)(((bb*3u + s)*24u + l)*2u + (q >> 1))) << 14;
        outp[obase + c0 + ncol0] = aN0[r] + g.x * b2a0 + g.y * b2b0;
        outp[obase + c0 + ncol1] = aN1[r] + g.x * b2a1 + g.y * b2b1;
      }
    }
  }
}

// ---------- aux ----------
__global__ void kaux(const int* __restrict__ ctr, float* __restrict__ outp) {
  const float* ps = (const float*)&ctr[C_PSUM];
  const float* ls = (const float*)&ctr[C_LSUM];
  float aux = 0.f;
  for (int s = 0; s < 3; ++s) {
    float acc = 0.f;
    for (int e = 0; e < 8; ++e) acc += ps[s*8+e] * ls[s*8+e];
    float v = 8.f * acc / (3072.f * 3072.f) - 1.f;
    aux += fmaxf(v, 0.f);
  }
  outp[2 * AOUT] = aux;
}

extern "C" void kernel_launch(void* const* d_in, const int* in_sizes, int n_in,
                              void* d_out, int out_size, void* d_ws, size_t ws_size,
                              hipStream_t stream) {
  (void)in_sizes; (void)n_in; (void)out_size; (void)ws_size;
  const float* z   = (const float*)d_in[0];
  const float* emb = (const float*)d_in[1];
  const float* Wr  = (const float*)d_in[2];
  const float* br  = (const float*)d_in[3];
  const float* W1  = (const float*)d_in[4];
  const float* b1  = (const float*)d_in[5];
  const float* W2  = (const float*)d_in[6];
  const float* b2  = (const float*)d_in[7];
  float* outp = (float*)d_out;
  char* ws = (char*)d_ws;
  int*  ctr      = (int*)(ws + OFF_CTR);
  int*  tokKey   = (int*)(ws + OFF_TOKKEY);
  f2*   tokG     = (f2*)(ws + OFF_TOKG);
  int*  rowToken = (int*)(ws + OFF_ROWTOK);
  f2*   rowG     = (f2*)(ws + OFF_ROWG);
  int2* g1e      = (int2*)(ws + OFF_G1E);
  u16*  Amat     = (u16*)(ws + OFF_AMAT);
  u16*  W2n      = (u16*)(ws + OFF_W2N);
  u16*  W2Tn     = (u16*)(ws + OFF_W2TN);
  float* b2T     = (float*)(ws + OFF_B2T);

  hipLaunchKernelGGL(kzero,    dim3(1), dim3(512), 0, stream, ctr);
  hipLaunchKernelGGL(kprep_w2, dim3(512,4,8), dim3(256), 0, stream, W2, W2n, W2Tn);
  hipLaunchKernelGGL(kprep_b2, dim3(512), dim3(256), 0, stream, b2, b2T);
  hipLaunchKernelGGL(kroute,   dim3(144), dim3(256), 0, stream, z, emb, Wr, br, ctr, tokKey, tokG);
  hipLaunchKernelGGL(kscan,    dim3(1), dim3(1), 0, stream, ctr);
  hipLaunchKernelGGL(kscatter, dim3(36), dim3(256), 0, stream, ctr, tokKey, tokG, rowToken, rowG, g1e);
  hipLaunchKernelGGL(kgemm1,   dim3(144,8), dim3(256), 0, stream, z, emb, W1, b1, ctr, g1e, rowG, Amat);
  hipLaunchKernelGGL(kgemm2,   dim3(128,28), dim3(256), 0, stream, Amat, W2n,  b2,  ctr, rowToken, rowG, outp, 0);
  hipLaunchKernelGGL(kgemm2,   dim3(128,28), dim3(256), 0, stream, Amat, W2Tn, b2T, ctr, rowToken, rowG, outp + AOUT, 1);
  hipLaunchKernelGGL(kaux,     dim3(1), dim3(1), 0, stream, ctr, outp);
}